// Round 3
// baseline (911.790 us; speedup 1.0000x reference)
//
#include <hip/hip_runtime.h>
#include <hip/hip_bf16.h>
#include <stdint.h>

#define DEVI __device__ __forceinline__

typedef __attribute__((ext_vector_type(8))) __bf16 bf16x8;
typedef __attribute__((ext_vector_type(4))) float f32x4;

DEVI unsigned short f2b(float f) {
  union { float f; unsigned int u; } x; x.f = f;
  unsigned int u = x.u;
  return (unsigned short)((u + 0x7fffu + ((u >> 16) & 1u)) >> 16);
}

// ---------------- fp32 -> bf16 convert (vectorized) ----------------
__global__ void cvt_kernel(const float* __restrict__ in,
                           unsigned short* __restrict__ out, long n4) {
  long i = (long)blockIdx.x * blockDim.x + threadIdx.x;
  long stride = (long)gridDim.x * blockDim.x;
  for (; i < n4; i += stride) {
    float4 v = reinterpret_cast<const float4*>(in)[i];
    ushort4 o;
    o.x = f2b(v.x); o.y = f2b(v.y); o.z = f2b(v.z); o.w = f2b(v.w);
    reinterpret_cast<ushort4*>(out)[i] = o;
  }
}

// ------------- [b][P][D] fp32 -> [b][D][P] bf16 transpose -------------
__global__ void transpose_cvt_kernel(const float* __restrict__ in,
                                     unsigned short* __restrict__ out,
                                     int P, int D) {
  __shared__ unsigned short tile[32][33];
  int b = blockIdx.z;
  int d0 = blockIdx.x * 32, p0 = blockIdx.y * 32;
  const float* src = in + (long)b * P * D;
  unsigned short* dst = out + (long)b * D * P;
  int tx = threadIdx.x & 31, ty = threadIdx.x >> 5; // 32 x 8
  for (int i = 0; i < 32; i += 8)
    tile[ty + i][tx] = f2b(src[(long)(p0 + ty + i) * D + d0 + tx]);
  __syncthreads();
  for (int i = 0; i < 32; i += 8)
    dst[(long)(d0 + ty + i) * P + p0 + tx] = tile[tx][ty + i];
}

// ---- u[y] = sum_d W[d][y] * v[d]   (atomic-split column GEMV) ----
__global__ void gemv_col_kernel(const float* __restrict__ W,
                                const float* __restrict__ v,
                                float* __restrict__ u, int D) {
  int y = blockIdx.x * 256 + threadIdx.x;
  int d0 = blockIdx.y * 128;
  float s = 0.f;
  for (int d = d0; d < d0 + 128; ++d) s += W[(long)d * D + y] * v[d];
  atomicAdd(&u[y], s);
}

// ---- c[row] = sum_y feat[row][y] * u[y]  (one wave per row) ----
__global__ void rowdot_kernel(const float* __restrict__ feat,
                              const float* __restrict__ u,
                              float* __restrict__ c, int D) {
  long row = (long)blockIdx.x * 4 + (threadIdx.x >> 6);
  int lane = threadIdx.x & 63;
  const float4* fr = (const float4*)(feat + row * D);
  const float4* uv = (const float4*)u;
  float s = 0.f;
  for (int j = lane; j < D / 4; j += 64) {
    float4 f = fr[j], g = uv[j];
    s += f.x * g.x + f.y * g.y + f.z * g.z + f.w * g.w;
  }
#pragma unroll
  for (int o = 32; o > 0; o >>= 1) s += __shfl_xor(s, o, 64);
  if (lane == 0) c[row] = s;
}

// ---------------- async global->LDS 16B ----------------
DEVI void gll16(const void* g, void* l) {
  __builtin_amdgcn_global_load_lds(
      (const __attribute__((address_space(1))) unsigned int*)g,
      (__attribute__((address_space(3))) unsigned int*)l, 16, 0, 0);
}

#define BAR() asm volatile("s_barrier" ::: "memory")
#define VMCNT4() asm volatile("s_waitcnt vmcnt(4)" ::: "memory")

// ======== 256x256 8-phase NT GEMM (bf16 out, no bias): C = A * B^T ========
// A [M][K], B [N][K] bf16 row-major; M,N mult of 256; K mult of 128.
// 512 threads = 8 waves (2 wm x 4 wn); per-wave C = 128x64.
// LDS: per matrix a ring of 4 K-slab slots (slab = 256 rows x 32 K = 16 KB),
// fragment-linear layout: frag f (16 rows x 32 K) occupies 1024 contiguous
// bytes, lane l's 16 B at f*1024 + l*16  ->  conflict-free ds_read_b128.
// Staging issues 6 phases ahead; vmcnt(4) at phases 4 & 8 guarantees the
// slabs consumed in the next 4 phases; end-of-phase barrier makes slot
// overwrite (issued phase 2q-5) safe vs prev occupant's last read (2q-6).
__global__ __launch_bounds__(512, 1) void gemm8_nt_kernel(
    const unsigned short* __restrict__ A,
    const unsigned short* __restrict__ B,
    unsigned short* __restrict__ C,
    int M, int N, int K) {
  __shared__ unsigned short lds[65536];  // 128 KiB: A slots [4][8192], B at +32768

  const int tid = threadIdx.x;
  const int lane = tid & 63;
  const int wid = tid >> 6;
  const int wm = wid >> 2, wn = wid & 3;
  const int m0 = blockIdx.y * 256;
  const int n0 = blockIdx.x * 256;
  const int lrow = lane & 15, lkq = lane >> 4;

  // per-lane global source bases for staging (frag f = i*8 + wid)
  const unsigned short* Ag0 = A + (long)(m0 + wid * 16 + lrow) * K + lkq * 8;
  const unsigned short* Ag1 = A + (long)(m0 + (8 + wid) * 16 + lrow) * K + lkq * 8;
  const unsigned short* Bg0 = B + (long)(n0 + wid * 16 + lrow) * K + lkq * 8;
  const unsigned short* Bg1 = B + (long)(n0 + (8 + wid) * 16 + lrow) * K + lkq * 8;

  auto stageA = [&](int q) {
    unsigned short* s = lds + (q & 3) * 8192;
    gll16(Ag0 + q * 32, (void*)(s + wid * 512));
    gll16(Ag1 + q * 32, (void*)(s + (8 + wid) * 512));
  };
  auto stageB = [&](int q) {
    unsigned short* s = lds + 32768 + (q & 3) * 8192;
    gll16(Bg0 + q * 32, (void*)(s + wid * 512));
    gll16(Bg1 + q * 32, (void*)(s + (8 + wid) * 512));
  };

  f32x4 acc[8][4];
#pragma unroll
  for (int mi = 0; mi < 8; ++mi)
#pragma unroll
    for (int n = 0; n < 4; ++n) acc[mi][n] = (f32x4){0.f, 0.f, 0.f, 0.f};

  const int NSLAB = K >> 5;
  const int NIT = K >> 7;

  // prologue: slabs 0,1,2 issued; vmcnt(4) -> slabs 0,1 complete
  stageA(0); stageB(0); stageA(1); stageB(1); stageA(2); stageB(2);
  VMCNT4();
  BAR();

  for (int it = 0; it < NIT; ++it) {
#pragma unroll
    for (int p = 1; p <= 8; ++p) {
      const int c = it * 4 + ((p - 1) >> 1);  // slab being computed
      const int mh = (p - 1) & 1;             // m-half of the wave's 8 m-frags
      const unsigned short* sA = lds + (c & 3) * 8192;
      const unsigned short* sB = lds + 32768 + (c & 3) * 8192;

      bf16x8 af[4], bfr[4];
#pragma unroll
      for (int j = 0; j < 4; ++j)
        af[j] = *reinterpret_cast<const bf16x8*>(sA + (wm * 8 + mh * 4 + j) * 512 + lane * 8);
#pragma unroll
      for (int n = 0; n < 4; ++n)
        bfr[n] = *reinterpret_cast<const bf16x8*>(sB + (wn * 4 + n) * 512 + lane * 8);

      if (p & 1) {
        const int q = it * 4 + ((p + 5) >> 1);
        if (q < NSLAB) stageA(q);
      } else {
        const int q = it * 4 + ((p + 4) >> 1);
        if (q < NSLAB) stageB(q);
      }
      if ((p & 3) == 0) VMCNT4();
      BAR();

      __builtin_amdgcn_s_setprio(1);
#pragma unroll
      for (int j = 0; j < 4; ++j)
#pragma unroll
        for (int n = 0; n < 4; ++n)
          acc[mh * 4 + j][n] =
              __builtin_amdgcn_mfma_f32_16x16x32_bf16(af[j], bfr[n], acc[mh * 4 + j][n], 0, 0, 0);
      __builtin_amdgcn_s_setprio(0);
      BAR();
    }
  }

  // epilogue: C[m0+wm*128+mi*16+lkq*4+r][n0+wn*64+n*16+lrow]
#pragma unroll
  for (int mi = 0; mi < 8; ++mi)
#pragma unroll
    for (int n = 0; n < 4; ++n) {
      const int gr0 = m0 + wm * 128 + mi * 16 + lkq * 4;
      const int gc = n0 + wn * 64 + n * 16 + lrow;
#pragma unroll
      for (int r = 0; r < 4; ++r)
        C[(long)(gr0 + r) * N + gc] = f2b(acc[mi][n][r]);
    }
}

// ---------------- generic NT GEMM (m97-style): C = (A * B^T + colbias) * scale ----------------
template<int OUT_BF16, int HAS_BIAS, int CLAMP_N>
__global__ __launch_bounds__(256, 2) void gemm_nt_kernel(
    const unsigned short* __restrict__ A,
    const unsigned short* __restrict__ B,
    void* __restrict__ Cv,
    const float* __restrict__ bias,
    float scale, int M, int N, int K,
    long sA, long sB, long sC, long sBias) {
  __shared__ unsigned short As[128 * 32];
  __shared__ unsigned short Bs[128 * 32];

  const int tid = threadIdx.x;
  const int lane = tid & 63;
  const int wid = tid >> 6;
  const int b = blockIdx.z;
  const int n0 = blockIdx.x * 128;
  const int m0 = blockIdx.y * 128;

  const unsigned short* Ab = A + (long)b * sA;
  const unsigned short* Bb = B + (long)b * sB;
  const float* biasb = HAS_BIAS ? bias + (long)b * sBias : nullptr;

  const int srow = lane >> 2;
  const int scol = (lane & 3) * 8;

  f32x4 acc[4][4];
#pragma unroll
  for (int m = 0; m < 4; ++m)
#pragma unroll
    for (int n = 0; n < 4; ++n) acc[m][n] = (f32x4){0.f, 0.f, 0.f, 0.f};

  const int wm = wid >> 1;
  const int wn = wid & 1;
  const int lrow = lane & 15;
  const int lkb = (lane >> 4) * 8;

  for (int k0 = 0; k0 < K; k0 += 32) {
#pragma unroll
    for (int i = 0; i < 2; ++i) {
      const int j = wid * 2 + i;
      const int ra = m0 + j * 16 + srow;
      gll16(Ab + (long)ra * K + k0 + scol, (void*)(As + j * 512));
      int rb = n0 + j * 16 + srow;
      if (CLAMP_N) rb = min(rb, N - 1);
      gll16(Bb + (long)rb * K + k0 + scol, (void*)(Bs + j * 512));
    }
    __syncthreads();

    bf16x8 af[4], bfr[4];
#pragma unroll
    for (int m = 0; m < 4; ++m)
      af[m] = *reinterpret_cast<const bf16x8*>(&As[(wm * 64 + m * 16 + lrow) * 32 + lkb]);
#pragma unroll
    for (int n = 0; n < 4; ++n)
      bfr[n] = *reinterpret_cast<const bf16x8*>(&Bs[(wn * 64 + n * 16 + lrow) * 32 + lkb]);
#pragma unroll
    for (int m = 0; m < 4; ++m)
#pragma unroll
      for (int n = 0; n < 4; ++n)
        acc[m][n] = __builtin_amdgcn_mfma_f32_16x16x32_bf16(af[m], bfr[n], acc[m][n], 0, 0, 0);
    __syncthreads();
  }

  const int crow = (lane >> 4) * 4;
  const int ccol = lane & 15;
#pragma unroll
  for (int m = 0; m < 4; ++m) {
#pragma unroll
    for (int n = 0; n < 4; ++n) {
      const int gc = n0 + wn * 64 + n * 16 + ccol;
      if (CLAMP_N && gc >= N) continue;
      float bv = HAS_BIAS ? biasb[gc] : 0.f;
#pragma unroll
      for (int r = 0; r < 4; ++r) {
        const int gr = m0 + wm * 64 + m * 16 + crow + r;
        float v = (acc[m][n][r] + bv) * scale;
        long off = (long)b * sC + (long)gr * N + gc;
        if (OUT_BF16)
          ((unsigned short*)Cv)[off] = f2b(v);
        else
          ((float*)Cv)[off] = v;
      }
    }
  }
}

// ---------------- row softmax over P=576, fp32 in -> bf16 out ----------------
__global__ void softmax_kernel(const float* __restrict__ s,
                               unsigned short* __restrict__ attn) {
  const int P = 576;
  long row = (long)blockIdx.x * 4 + (threadIdx.x >> 6);
  int lane = threadIdx.x & 63;
  const float* sr = s + row * P;
  unsigned short* ar = attn + row * P;
  float v[9];
  float mx = -3.0e38f;
#pragma unroll
  for (int j = 0; j < 9; ++j) {
    v[j] = sr[j * 64 + lane];
    mx = fmaxf(mx, v[j]);
  }
#pragma unroll
  for (int o = 32; o > 0; o >>= 1) mx = fmaxf(mx, __shfl_xor(mx, o, 64));
  float sum = 0.f;
#pragma unroll
  for (int j = 0; j < 9; ++j) {
    v[j] = __expf(v[j] - mx);
    sum += v[j];
  }
#pragma unroll
  for (int o = 32; o > 0; o >>= 1) sum += __shfl_xor(sum, o, 64);
  float inv = 1.0f / sum;
#pragma unroll
  for (int j = 0; j < 9; ++j) ar[j * 64 + lane] = f2b(v[j] * inv);
}

extern "C" void kernel_launch(void* const* d_in, const int* in_sizes, int n_in,
                              void* d_out, int out_size, void* d_ws, size_t ws_size,
                              hipStream_t stream) {
  const float* text = (const float*)d_in[0];
  const float* feat = (const float*)d_in[1];
  const float* Wq = (const float*)d_in[2];
  const float* bq = (const float*)d_in[3];
  const float* Wk = (const float*)d_in[4];
  const float* bk = (const float*)d_in[5];
  (void)bk;  // bk's contribution to scores is constant over p -> softmax-invariant

  const int B = 8, T = 2048, P = 576, D = 4096;
  const long nText = (long)B * T * D;  // 67,108,864
  const long nFeat = (long)B * P * D;  // 18,874,368

  char* ws = (char*)d_ws;
  unsigned short* text_b = (unsigned short*)(ws);              // 134,217,728
  unsigned short* feat_b = (unsigned short*)(ws + 134217728);  //  37,748,736
  unsigned short* fT_b   = (unsigned short*)(ws + 171966464);  //  37,748,736
  unsigned short* WqT_b  = (unsigned short*)(ws + 209715200);  //  33,554,432
  unsigned short* WkT_b  = (unsigned short*)(ws + 243269632);  //  33,554,432
  unsigned short* attn_b = (unsigned short*)(ws + 276824064);  //  18,874,368
  float* u               = (float*)(ws + 295698432);           //      16,384
  float* c               = (float*)(ws + 295714816);           //      18,432
  float* scores          = (float*)(ws + 209715200);           // alias over WqT/WkT (dead after W2T)
  unsigned short* W2T_b  = (unsigned short*)d_out;                     // head of d_out
  unsigned short* KW_b   = (unsigned short*)((char*)d_out + 67108864); // +64 MB

  dim3 blk(256);
  cvt_kernel<<<4096, blk, 0, stream>>>(text, text_b, nText / 4);
  cvt_kernel<<<2048, blk, 0, stream>>>(feat, feat_b, nFeat / 4);
  transpose_cvt_kernel<<<dim3(D / 32, P / 32, B), blk, 0, stream>>>(feat, fT_b, P, D);
  transpose_cvt_kernel<<<dim3(D / 32, D / 32, 1), blk, 0, stream>>>(Wq, WqT_b, D, D);
  transpose_cvt_kernel<<<dim3(D / 32, D / 32, 1), blk, 0, stream>>>(Wk, WkT_b, D, D);
  hipMemsetAsync(u, 0, D * sizeof(float), stream);
  gemv_col_kernel<<<dim3(D / 256, 32), blk, 0, stream>>>(Wk, bq, u, D);
  rowdot_kernel<<<(B * P) / 4, blk, 0, stream>>>(feat, u, c, D);

  // W2T[x][y] = sum_d Wq[d,x] Wk[d,y] : 8-phase 256^2
  gemm8_nt_kernel<<<dim3(16, 16), dim3(512), 0, stream>>>(
      WqT_b, WkT_b, W2T_b, D, D, D);
  // KW[bp][x] = sum_y feat[bp,y] W2T[x,y] : 8-phase 256^2
  gemm8_nt_kernel<<<dim3(16, 18), dim3(512), 0, stream>>>(
      feat_b, W2T_b, KW_b, B * P, D, D);
  // scores[b][t][p] = (text[t,:].KW[b,p,:] + c[b,p]) / 64 : fp32 out, N clamped
  gemm_nt_kernel<0, 1, 1><<<dim3(5, 16, 8), blk, 0, stream>>>(
      text_b, KW_b, scores, c, 1.0f / 64.0f, T, P, D,
      (long)T * D, (long)P * D, (long)T * P, P);
  softmax_kernel<<<(B * T) / 4, blk, 0, stream>>>(scores, attn_b);
  // attended = attn * featT^T
  gemm_nt_kernel<0, 0, 0><<<dim3(32, 16, 8), blk, 0, stream>>>(
      attn_b, fT_b, (float*)d_out, nullptr, 1.0f, T, D, P,
      (long)T * P, (long)D * P, (long)T * D, 0);
}

// Round 4
// 848.875 us; speedup vs baseline: 1.0741x; 1.0741x over previous
//
#include <hip/hip_runtime.h>
#include <hip/hip_bf16.h>
#include <stdint.h>

#define DEVI __device__ __forceinline__

typedef __attribute__((ext_vector_type(8))) __bf16 bf16x8;
typedef __attribute__((ext_vector_type(4))) float f32x4;

DEVI unsigned short f2b(float f) {
  union { float f; unsigned int u; } x; x.f = f;
  unsigned int u = x.u;
  return (unsigned short)((u + 0x7fffu + ((u >> 16) & 1u)) >> 16);
}

// ---------------- fp32 -> bf16 convert (vectorized) ----------------
__global__ void cvt_kernel(const float* __restrict__ in,
                           unsigned short* __restrict__ out, long n4) {
  long i = (long)blockIdx.x * blockDim.x + threadIdx.x;
  long stride = (long)gridDim.x * blockDim.x;
  for (; i < n4; i += stride) {
    float4 v = reinterpret_cast<const float4*>(in)[i];
    ushort4 o;
    o.x = f2b(v.x); o.y = f2b(v.y); o.z = f2b(v.z); o.w = f2b(v.w);
    reinterpret_cast<ushort4*>(out)[i] = o;
  }
}

// ------------- [b][P][D] fp32 -> [b][D][P] bf16 transpose -------------
__global__ void transpose_cvt_kernel(const float* __restrict__ in,
                                     unsigned short* __restrict__ out,
                                     int P, int D) {
  __shared__ unsigned short tile[32][33];
  int b = blockIdx.z;
  int d0 = blockIdx.x * 32, p0 = blockIdx.y * 32;
  const float* src = in + (long)b * P * D;
  unsigned short* dst = out + (long)b * D * P;
  int tx = threadIdx.x & 31, ty = threadIdx.x >> 5; // 32 x 8
  for (int i = 0; i < 32; i += 8)
    tile[ty + i][tx] = f2b(src[(long)(p0 + ty + i) * D + d0 + tx]);
  __syncthreads();
  for (int i = 0; i < 32; i += 8)
    dst[(long)(d0 + ty + i) * P + p0 + tx] = tile[tx][ty + i];
}

// ---- u[y] = sum_d W[d][y] * v[d]   (atomic-split column GEMV) ----
__global__ void gemv_col_kernel(const float* __restrict__ W,
                                const float* __restrict__ v,
                                float* __restrict__ u, int D) {
  int y = blockIdx.x * 256 + threadIdx.x;
  int d0 = blockIdx.y * 128;
  float s = 0.f;
  for (int d = d0; d < d0 + 128; ++d) s += W[(long)d * D + y] * v[d];
  atomicAdd(&u[y], s);
}

// ---- c[row] = sum_y feat[row][y] * u[y]  (one wave per row) ----
__global__ void rowdot_kernel(const float* __restrict__ feat,
                              const float* __restrict__ u,
                              float* __restrict__ c, int D) {
  long row = (long)blockIdx.x * 4 + (threadIdx.x >> 6);
  int lane = threadIdx.x & 63;
  const float4* fr = (const float4*)(feat + row * D);
  const float4* uv = (const float4*)u;
  float s = 0.f;
  for (int j = lane; j < D / 4; j += 64) {
    float4 f = fr[j], g = uv[j];
    s += f.x * g.x + f.y * g.y + f.z * g.z + f.w * g.w;
  }
#pragma unroll
  for (int o = 32; o > 0; o >>= 1) s += __shfl_xor(s, o, 64);
  if (lane == 0) c[row] = s;
}

// ---------------- async global->LDS 16B ----------------
DEVI void gll16(const void* g, void* l) {
  __builtin_amdgcn_global_load_lds(
      (const __attribute__((address_space(1))) unsigned int*)g,
      (__attribute__((address_space(3))) unsigned int*)l, 16, 0, 0);
}

// ---------------- generic NT GEMM: C = (A * B^T + colbias) * scale ----------------
// A [M][K] bf16 row-major, B [N][K] bf16 row-major, C [M][N].
// 128x128 tile, BK=32, 256 threads (4 waves, each 64x64), mfma 16x16x32 bf16.
// XCD-aware bijective swizzle of the flattened (x,y) grid per z-slice.
template<int OUT_BF16, int HAS_BIAS, int CLAMP_N>
__global__ __launch_bounds__(256, 4) void gemm_nt_kernel(
    const unsigned short* __restrict__ A,
    const unsigned short* __restrict__ B,
    void* __restrict__ Cv,
    const float* __restrict__ bias,
    float scale, int M, int N, int K,
    long sA, long sB, long sC, long sBias) {
  __shared__ unsigned short As[128 * 32];
  __shared__ unsigned short Bs[128 * 32];

  const int tid = threadIdx.x;
  const int lane = tid & 63;
  const int wid = tid >> 6;
  const int b = blockIdx.z;

  // bijective XCD swizzle over flattened (x,y)
  const int gx = gridDim.x;
  const int nwg = gx * gridDim.y;
  int wg = blockIdx.y * gx + blockIdx.x;
  {
    const int q = nwg >> 3, r = nwg & 7;
    const int xcd = wg & 7, loc = wg >> 3;
    wg = (xcd < r ? xcd * (q + 1) : r * (q + 1) + (xcd - r) * q) + loc;
  }
  const int n0 = (wg % gx) * 128;
  const int m0 = (wg / gx) * 128;

  const unsigned short* Ab = A + (long)b * sA;
  const unsigned short* Bb = B + (long)b * sB;
  const float* biasb = HAS_BIAS ? bias + (long)b * sBias : nullptr;

  const int srow = lane >> 2;       // 0..15 : row within 16-row staging stripe
  const int scol = (lane & 3) * 8;  // bf16 element offset within 32-wide K slab

  f32x4 acc[4][4];
#pragma unroll
  for (int m = 0; m < 4; ++m)
#pragma unroll
    for (int n = 0; n < 4; ++n) acc[m][n] = (f32x4){0.f, 0.f, 0.f, 0.f};

  const int wm = wid >> 1;           // wave tile (64x64) coords
  const int wn = wid & 1;
  const int lrow = lane & 15;        // fragment row
  const int lkb = (lane >> 4) * 8;   // fragment k offset (bf16 elems)

  for (int k0 = 0; k0 < K; k0 += 32) {
#pragma unroll
    for (int i = 0; i < 2; ++i) {
      const int j = wid * 2 + i;           // wave-uniform stripe id 0..7
      const int ra = m0 + j * 16 + srow;
      gll16(Ab + (long)ra * K + k0 + scol, (void*)(As + j * 512));
      int rb = n0 + j * 16 + srow;
      if (CLAMP_N) rb = min(rb, N - 1);
      gll16(Bb + (long)rb * K + k0 + scol, (void*)(Bs + j * 512));
    }
    __syncthreads();

    bf16x8 af[4], bfr[4];
#pragma unroll
    for (int m = 0; m < 4; ++m)
      af[m] = *reinterpret_cast<const bf16x8*>(&As[(wm * 64 + m * 16 + lrow) * 32 + lkb]);
#pragma unroll
    for (int n = 0; n < 4; ++n)
      bfr[n] = *reinterpret_cast<const bf16x8*>(&Bs[(wn * 64 + n * 16 + lrow) * 32 + lkb]);
#pragma unroll
    for (int m = 0; m < 4; ++m)
#pragma unroll
      for (int n = 0; n < 4; ++n)
        acc[m][n] = __builtin_amdgcn_mfma_f32_16x16x32_bf16(af[m], bfr[n], acc[m][n], 0, 0, 0);
    __syncthreads();
  }

  const int crow = (lane >> 4) * 4;
  const int ccol = lane & 15;
#pragma unroll
  for (int m = 0; m < 4; ++m) {
#pragma unroll
    for (int n = 0; n < 4; ++n) {
      const int gc = n0 + wn * 64 + n * 16 + ccol;
      if (CLAMP_N && gc >= N) continue;
      float bv = HAS_BIAS ? biasb[gc] : 0.f;
#pragma unroll
      for (int r = 0; r < 4; ++r) {
        const int gr = m0 + wm * 64 + m * 16 + crow + r;
        float v = (acc[m][n][r] + bv) * scale;
        long off = (long)b * sC + (long)gr * N + gc;
        if (OUT_BF16)
          ((unsigned short*)Cv)[off] = f2b(v);
        else
          ((float*)Cv)[off] = v;
      }
    }
  }
}

// ---------------- row softmax over P=576, fp32 in -> bf16 out ----------------
__global__ void softmax_kernel(const float* __restrict__ s,
                               unsigned short* __restrict__ attn) {
  const int P = 576;
  long row = (long)blockIdx.x * 4 + (threadIdx.x >> 6);
  int lane = threadIdx.x & 63;
  const float* sr = s + row * P;
  unsigned short* ar = attn + row * P;
  float v[9];
  float mx = -3.0e38f;
#pragma unroll
  for (int j = 0; j < 9; ++j) {
    v[j] = sr[j * 64 + lane];
    mx = fmaxf(mx, v[j]);
  }
#pragma unroll
  for (int o = 32; o > 0; o >>= 1) mx = fmaxf(mx, __shfl_xor(mx, o, 64));
  float sum = 0.f;
#pragma unroll
  for (int j = 0; j < 9; ++j) {
    v[j] = __expf(v[j] - mx);
    sum += v[j];
  }
#pragma unroll
  for (int o = 32; o > 0; o >>= 1) sum += __shfl_xor(sum, o, 64);
  float inv = 1.0f / sum;
#pragma unroll
  for (int j = 0; j < 9; ++j) ar[j * 64 + lane] = f2b(v[j] * inv);
}

extern "C" void kernel_launch(void* const* d_in, const int* in_sizes, int n_in,
                              void* d_out, int out_size, void* d_ws, size_t ws_size,
                              hipStream_t stream) {
  const float* text = (const float*)d_in[0];
  const float* feat = (const float*)d_in[1];
  const float* Wq = (const float*)d_in[2];
  const float* bq = (const float*)d_in[3];
  const float* Wk = (const float*)d_in[4];
  const float* bk = (const float*)d_in[5];
  (void)bk;  // bk's contribution to scores is constant over p -> softmax-invariant

  const int B = 8, T = 2048, P = 576, D = 4096;
  const long nText = (long)B * T * D;  // 67,108,864
  const long nFeat = (long)B * P * D;  // 18,874,368

  char* ws = (char*)d_ws;
  unsigned short* text_b = (unsigned short*)(ws);              // 134,217,728
  unsigned short* feat_b = (unsigned short*)(ws + 134217728);  //  37,748,736
  unsigned short* fT_b   = (unsigned short*)(ws + 171966464);  //  37,748,736
  unsigned short* WqT_b  = (unsigned short*)(ws + 209715200);  //  33,554,432
  unsigned short* WkT_b  = (unsigned short*)(ws + 243269632);  //  33,554,432
  unsigned short* attn_b = (unsigned short*)(ws + 276824064);  //  18,874,368
  float* u               = (float*)(ws + 295698432);           //      16,384
  float* c               = (float*)(ws + 295714816);           //      18,432
  float* scores          = (float*)(ws + 209715200);           // alias over WqT/WkT (dead after W2T)
  unsigned short* W2T_b  = (unsigned short*)d_out;                     // head of d_out
  unsigned short* KW_b   = (unsigned short*)((char*)d_out + 67108864); // +64 MB

  dim3 blk(256);
  cvt_kernel<<<4096, blk, 0, stream>>>(text, text_b, nText / 4);
  cvt_kernel<<<2048, blk, 0, stream>>>(feat, feat_b, nFeat / 4);
  transpose_cvt_kernel<<<dim3(D / 32, P / 32, B), blk, 0, stream>>>(feat, fT_b, P, D);
  transpose_cvt_kernel<<<dim3(D / 32, D / 32, 1), blk, 0, stream>>>(Wq, WqT_b, D, D);
  transpose_cvt_kernel<<<dim3(D / 32, D / 32, 1), blk, 0, stream>>>(Wk, WkT_b, D, D);
  hipMemsetAsync(u, 0, D * sizeof(float), stream);
  gemv_col_kernel<<<dim3(D / 256, 32), blk, 0, stream>>>(Wk, bq, u, D);
  rowdot_kernel<<<(B * P) / 4, blk, 0, stream>>>(feat, u, c, D);

  // W2T[x][y] = sum_d Wq[d,x] Wk[d,y]  : NT(WqT, WkT), bf16 out
  gemm_nt_kernel<1, 0, 0><<<dim3(32, 32, 1), blk, 0, stream>>>(
      WqT_b, WkT_b, W2T_b, nullptr, 1.0f, D, D, D, 0, 0, 0, 0);
  // KW[bp][x] = sum_y feat[bp,y] W2T[x,y] : NT(feat_b, W2T), bf16 out
  gemm_nt_kernel<1, 0, 0><<<dim3(32, 36, 1), blk, 0, stream>>>(
      feat_b, W2T_b, KW_b, nullptr, 1.0f, B * P, D, D, 0, 0, 0, 0);
  // scores[b][t][p] = (text[t,:].KW[b,p,:] + c[b,p]) / 64 : fp32 out, N clamped
  gemm_nt_kernel<0, 1, 1><<<dim3(5, 16, 8), blk, 0, stream>>>(
      text_b, KW_b, scores, c, 1.0f / 64.0f, T, P, D,
      (long)T * D, (long)P * D, (long)T * P, P);
  softmax_kernel<<<(B * T) / 4, blk, 0, stream>>>(scores, attn_b);
  // attended = attn * featT^T
  gemm_nt_kernel<0, 0, 0><<<dim3(32, 16, 8), blk, 0, stream>>>(
      attn_b, fT_b, (float*)d_out, nullptr, 1.0f, T, D, P,
      (long)T * P, (long)D * P, (long)T * D, 0);
}

// Round 5
// 833.981 us; speedup vs baseline: 1.0933x; 1.0179x over previous
//
#include <hip/hip_runtime.h>
#include <hip/hip_bf16.h>
#include <stdint.h>

#define DEVI __device__ __forceinline__

typedef __attribute__((ext_vector_type(8))) __bf16 bf16x8;
typedef __attribute__((ext_vector_type(4))) float f32x4;

DEVI unsigned short f2b(float f) {
  union { float f; unsigned int u; } x; x.f = f;
  unsigned int u = x.u;
  return (unsigned short)((u + 0x7fffu + ((u >> 16) & 1u)) >> 16);
}

// ---------------- fp32 -> bf16 convert (vectorized) ----------------
__global__ void cvt_kernel(const float* __restrict__ in,
                           unsigned short* __restrict__ out, long n4) {
  long i = (long)blockIdx.x * blockDim.x + threadIdx.x;
  long stride = (long)gridDim.x * blockDim.x;
  for (; i < n4; i += stride) {
    float4 v = reinterpret_cast<const float4*>(in)[i];
    ushort4 o;
    o.x = f2b(v.x); o.y = f2b(v.y); o.z = f2b(v.z); o.w = f2b(v.w);
    reinterpret_cast<ushort4*>(out)[i] = o;
  }
}

// ------------- [b][P][D] fp32 -> [b][D][P] bf16 transpose -------------
__global__ void transpose_cvt_kernel(const float* __restrict__ in,
                                     unsigned short* __restrict__ out,
                                     int P, int D) {
  __shared__ unsigned short tile[32][33];
  int b = blockIdx.z;
  int d0 = blockIdx.x * 32, p0 = blockIdx.y * 32;
  const float* src = in + (long)b * P * D;
  unsigned short* dst = out + (long)b * D * P;
  int tx = threadIdx.x & 31, ty = threadIdx.x >> 5; // 32 x 8
  for (int i = 0; i < 32; i += 8)
    tile[ty + i][tx] = f2b(src[(long)(p0 + ty + i) * D + d0 + tx]);
  __syncthreads();
  for (int i = 0; i < 32; i += 8)
    dst[(long)(d0 + ty + i) * P + p0 + tx] = tile[tx][ty + i];
}

// ---- u[y] = sum_d W[d][y] * v[d]   (atomic-split column GEMV) ----
__global__ void gemv_col_kernel(const float* __restrict__ W,
                                const float* __restrict__ v,
                                float* __restrict__ u, int D) {
  int y = blockIdx.x * 256 + threadIdx.x;
  int d0 = blockIdx.y * 128;
  float s = 0.f;
  for (int d = d0; d < d0 + 128; ++d) s += W[(long)d * D + y] * v[d];
  atomicAdd(&u[y], s);
}

// ---- c[row] = sum_y feat[row][y] * u[y]  (one wave per row) ----
__global__ void rowdot_kernel(const float* __restrict__ feat,
                              const float* __restrict__ u,
                              float* __restrict__ c, int D) {
  long row = (long)blockIdx.x * 4 + (threadIdx.x >> 6);
  int lane = threadIdx.x & 63;
  const float4* fr = (const float4*)(feat + row * D);
  const float4* uv = (const float4*)u;
  float s = 0.f;
  for (int j = lane; j < D / 4; j += 64) {
    float4 f = fr[j], g = uv[j];
    s += f.x * g.x + f.y * g.y + f.z * g.z + f.w * g.w;
  }
#pragma unroll
  for (int o = 32; o > 0; o >>= 1) s += __shfl_xor(s, o, 64);
  if (lane == 0) c[row] = s;
}

// ---------------- async global->LDS 16B ----------------
DEVI void gll16(const void* g, void* l) {
  __builtin_amdgcn_global_load_lds(
      (const __attribute__((address_space(1))) unsigned int*)g,
      (__attribute__((address_space(3))) unsigned int*)l, 16, 0, 0);
}

// ---------------- generic NT GEMM: C = (A * B^T + colbias) * scale ----------------
// A [M][K] bf16 row-major, B [N][K] bf16 row-major, C [M][N].
// 128x128 tile, BK=32, 256 threads (4 waves, each 64x64), mfma 16x16x32 bf16.
// 2-phase double-buffered staging (T3-minimum): issue next tile's
// global_load_lds BEFORE computing the current tile; single __syncthreads
// per K-iter drains them one full body later.
// BATCH_X: batch folded into blockIdx.x low 3 bits -> wg % 8 == b -> each
// XCD (round-robin dispatch) serves one batch; its B-panel stays in L2.
template<int OUT_BF16, int HAS_BIAS, int CLAMP_N, int BATCH_X>
__global__ __launch_bounds__(256, 3) void gemm_nt_kernel(
    const unsigned short* __restrict__ A,
    const unsigned short* __restrict__ B,
    void* __restrict__ Cv,
    const float* __restrict__ bias,
    float scale, int M, int N, int K,
    long sA, long sB, long sC, long sBias) {
  __shared__ unsigned short As[2][128 * 32];
  __shared__ unsigned short Bs[2][128 * 32];

  const int tid = threadIdx.x;
  const int lane = tid & 63;
  const int wid = tid >> 6;

  int bx = blockIdx.x;
  int b;
  if (BATCH_X) { b = bx & 7; bx >>= 3; } else { b = blockIdx.z; }
  const int n0 = bx * 128;
  const int m0 = blockIdx.y * 128;

  const unsigned short* Ab = A + (long)b * sA;
  const unsigned short* Bb = B + (long)b * sB;
  const float* biasb = HAS_BIAS ? bias + (long)b * sBias : nullptr;

  const int srow = lane >> 2;       // 0..15 : row within 16-row staging stripe
  const int scol = (lane & 3) * 8;  // bf16 element offset within 32-wide K slab

  auto stage = [&](int k0, int buf) {
#pragma unroll
    for (int i = 0; i < 2; ++i) {
      const int j = wid * 2 + i;           // wave-uniform stripe id 0..7
      const int ra = m0 + j * 16 + srow;
      gll16(Ab + (long)ra * K + k0 + scol, (void*)(As[buf] + j * 512));
      int rb = n0 + j * 16 + srow;
      if (CLAMP_N) rb = min(rb, N - 1);
      gll16(Bb + (long)rb * K + k0 + scol, (void*)(Bs[buf] + j * 512));
    }
  };

  f32x4 acc[4][4];
#pragma unroll
  for (int m = 0; m < 4; ++m)
#pragma unroll
    for (int n = 0; n < 4; ++n) acc[m][n] = (f32x4){0.f, 0.f, 0.f, 0.f};

  const int wm = wid >> 1;           // wave tile (64x64) coords
  const int wn = wid & 1;
  const int lrow = lane & 15;        // fragment row
  const int lkb = (lane >> 4) * 8;   // fragment k offset (bf16 elems)

  stage(0, 0);
  __syncthreads();

  int cur = 0;
  for (int k0 = 0; k0 < K; k0 += 32) {
    if (k0 + 32 < K) stage(k0 + 32, cur ^ 1);  // prefetch next tile first

    bf16x8 af[4], bfr[4];
#pragma unroll
    for (int m = 0; m < 4; ++m)
      af[m] = *reinterpret_cast<const bf16x8*>(&As[cur][(wm * 64 + m * 16 + lrow) * 32 + lkb]);
#pragma unroll
    for (int n = 0; n < 4; ++n)
      bfr[n] = *reinterpret_cast<const bf16x8*>(&Bs[cur][(wn * 64 + n * 16 + lrow) * 32 + lkb]);
#pragma unroll
    for (int m = 0; m < 4; ++m)
#pragma unroll
      for (int n = 0; n < 4; ++n)
        acc[m][n] = __builtin_amdgcn_mfma_f32_16x16x32_bf16(af[m], bfr[n], acc[m][n], 0, 0, 0);

    __syncthreads();  // drains prefetch (issued one body ago) + orders buffers
    cur ^= 1;
  }

  const int crow = (lane >> 4) * 4;
  const int ccol = lane & 15;
#pragma unroll
  for (int m = 0; m < 4; ++m) {
#pragma unroll
    for (int n = 0; n < 4; ++n) {
      const int gc = n0 + wn * 64 + n * 16 + ccol;
      if (CLAMP_N && gc >= N) continue;
      float bv = HAS_BIAS ? biasb[gc] : 0.f;
#pragma unroll
      for (int r = 0; r < 4; ++r) {
        const int gr = m0 + wm * 64 + m * 16 + crow + r;
        float v = (acc[m][n][r] + bv) * scale;
        long off = (long)b * sC + (long)gr * N + gc;
        if (OUT_BF16)
          ((unsigned short*)Cv)[off] = f2b(v);
        else
          ((float*)Cv)[off] = v;
      }
    }
  }
}

// ---------------- row softmax over P=576, fp32 in -> bf16 out ----------------
__global__ void softmax_kernel(const float* __restrict__ s,
                               unsigned short* __restrict__ attn) {
  const int P = 576;
  long row = (long)blockIdx.x * 4 + (threadIdx.x >> 6);
  int lane = threadIdx.x & 63;
  const float* sr = s + row * P;
  unsigned short* ar = attn + row * P;
  float v[9];
  float mx = -3.0e38f;
#pragma unroll
  for (int j = 0; j < 9; ++j) {
    v[j] = sr[j * 64 + lane];
    mx = fmaxf(mx, v[j]);
  }
#pragma unroll
  for (int o = 32; o > 0; o >>= 1) mx = fmaxf(mx, __shfl_xor(mx, o, 64));
  float sum = 0.f;
#pragma unroll
  for (int j = 0; j < 9; ++j) {
    v[j] = __expf(v[j] - mx);
    sum += v[j];
  }
#pragma unroll
  for (int o = 32; o > 0; o >>= 1) sum += __shfl_xor(sum, o, 64);
  float inv = 1.0f / sum;
#pragma unroll
  for (int j = 0; j < 9; ++j) ar[j * 64 + lane] = f2b(v[j] * inv);
}

extern "C" void kernel_launch(void* const* d_in, const int* in_sizes, int n_in,
                              void* d_out, int out_size, void* d_ws, size_t ws_size,
                              hipStream_t stream) {
  const float* text = (const float*)d_in[0];
  const float* feat = (const float*)d_in[1];
  const float* Wq = (const float*)d_in[2];
  const float* bq = (const float*)d_in[3];
  const float* Wk = (const float*)d_in[4];
  const float* bk = (const float*)d_in[5];
  (void)bk;  // bk's contribution to scores is constant over p -> softmax-invariant

  const int B = 8, T = 2048, P = 576, D = 4096;
  const long nText = (long)B * T * D;  // 67,108,864
  const long nFeat = (long)B * P * D;  // 18,874,368

  char* ws = (char*)d_ws;
  unsigned short* text_b = (unsigned short*)(ws);              // 134,217,728
  unsigned short* feat_b = (unsigned short*)(ws + 134217728);  //  37,748,736
  unsigned short* fT_b   = (unsigned short*)(ws + 171966464);  //  37,748,736
  unsigned short* WqT_b  = (unsigned short*)(ws + 209715200);  //  33,554,432
  unsigned short* WkT_b  = (unsigned short*)(ws + 243269632);  //  33,554,432
  unsigned short* attn_b = (unsigned short*)(ws + 276824064);  //  18,874,368
  float* u               = (float*)(ws + 295698432);           //      16,384
  float* c               = (float*)(ws + 295714816);           //      18,432
  float* scores          = (float*)(ws + 209715200);           // alias over WqT/WkT (dead after W2T)
  unsigned short* W2T_b  = (unsigned short*)d_out;                     // head of d_out
  unsigned short* KW_b   = (unsigned short*)((char*)d_out + 67108864); // +64 MB

  dim3 blk(256);
  cvt_kernel<<<4096, blk, 0, stream>>>(text, text_b, nText / 4);
  cvt_kernel<<<2048, blk, 0, stream>>>(feat, feat_b, nFeat / 4);
  transpose_cvt_kernel<<<dim3(D / 32, P / 32, B), blk, 0, stream>>>(feat, fT_b, P, D);
  transpose_cvt_kernel<<<dim3(D / 32, D / 32, 1), blk, 0, stream>>>(Wq, WqT_b, D, D);
  transpose_cvt_kernel<<<dim3(D / 32, D / 32, 1), blk, 0, stream>>>(Wk, WkT_b, D, D);
  hipMemsetAsync(u, 0, D * sizeof(float), stream);
  gemv_col_kernel<<<dim3(D / 256, 32), blk, 0, stream>>>(Wk, bq, u, D);
  rowdot_kernel<<<(B * P) / 4, blk, 0, stream>>>(feat, u, c, D);

  // W2T[x][y] = sum_d Wq[d,x] Wk[d,y]  : NT(WqT, WkT), bf16 out
  gemm_nt_kernel<1, 0, 0, 0><<<dim3(32, 32, 1), blk, 0, stream>>>(
      WqT_b, WkT_b, W2T_b, nullptr, 1.0f, D, D, D, 0, 0, 0, 0);
  // KW[bp][x] = sum_y feat[bp,y] W2T[x,y] : NT(feat_b, W2T), bf16 out
  gemm_nt_kernel<1, 0, 0, 0><<<dim3(32, 36, 1), blk, 0, stream>>>(
      feat_b, W2T_b, KW_b, nullptr, 1.0f, B * P, D, D, 0, 0, 0, 0);
  // scores[b][t][p] = (text[t,:].KW[b,p,:] + c[b,p]) / 64 : fp32, batch->XCD
  gemm_nt_kernel<0, 1, 1, 1><<<dim3(40, 16, 1), blk, 0, stream>>>(
      text_b, KW_b, scores, c, 1.0f / 64.0f, T, P, D,
      (long)T * D, (long)P * D, (long)T * P, P);
  softmax_kernel<<<(B * T) / 4, blk, 0, stream>>>(scores, attn_b);
  // attended = attn * featT^T : batch->XCD
  gemm_nt_kernel<0, 0, 0, 1><<<dim3(256, 16, 1), blk, 0, stream>>>(
      attn_b, fT_b, (float*)d_out, nullptr, 1.0f, T, D, P,
      (long)T * P, (long)D * P, (long)T * D, 0);
}